// Round 1
// baseline (40.702 us; speedup 1.0000x reference)
//
#include <hip/hip_runtime.h>
#include <hip/hip_bf16.h>
#include <stdint.h>

// Problem constants
// x: (32, 128, 28, 28) f32 ; W: (128, 128, 3, 3) f32
// pad = 2, ho = wo = 30, L = 30*30*32 = 28800, K = 1152, F = 128
// out: (32, 128, 30, 30) f32, out[n,f,i,j] = sum_k W[f,k]*patch[n,i,j,k] - 0.5||W_f||^2 - 0.5||X_l||^2

#define N_IMG 32
#define C_IN 128
#define H_IN 28
#define HP 32            // padded H/W
#define HO 30
#define P_SP (HO*HO)     // 900 spatial positions
#define L_TOT (P_SP*N_IMG) // 28800
#define F_OUT 128
#define K_TOT 1152

typedef __attribute__((ext_vector_type(8))) short bf16x8;
typedef __attribute__((ext_vector_type(4))) float f32x4;

__device__ __forceinline__ unsigned short f2bf(float f) {
  union { float f; unsigned u; } t; t.f = f;
  unsigned r = t.u + 0x7fffu + ((t.u >> 16) & 1u);
  return (unsigned short)(r >> 16);
}

// ---------------------------------------------------------------------------
// Kernel 1: pad + convert x to channels-last bf16, and per-pixel sum_c x^2
// xcl[n][hp][wp][c] (bf16), s[n][hp][wp] (f32), hp/wp in [0,32)
// grid (32, 32) = (n, hp), block 256
// ---------------------------------------------------------------------------
__global__ void prep_x_kernel(const float* __restrict__ x,
                              unsigned short* __restrict__ xcl,
                              float* __restrict__ s) {
  int n = blockIdx.x, hp = blockIdx.y;
  __shared__ float row[C_IN * H_IN];   // 128*28 f32 = 14336 B
  bool interior = (hp >= 2 && hp < 2 + H_IN);
  int h = hp - 2;
  if (interior) {
    for (int idx = threadIdx.x; idx < C_IN * H_IN; idx += 256) {
      int c = idx / H_IN, w = idx % H_IN;
      row[c * H_IN + w] = x[((n * C_IN + c) * H_IN + h) * H_IN + w];
    }
  }
  __syncthreads();
  // write xcl row (zero in padding)
  for (int idx = threadIdx.x; idx < HP * C_IN; idx += 256) {
    int wp = idx >> 7, c = idx & 127;
    float v = 0.f;
    if (interior && wp >= 2 && wp < 2 + H_IN) v = row[c * H_IN + (wp - 2)];
    xcl[((n * HP + hp) * HP + wp) * C_IN + c] = f2bf(v);
  }
  // squared channel sums: 8 threads per wp
  int wp = threadIdx.x >> 3, l8 = threadIdx.x & 7;
  float sum = 0.f;
  if (interior && wp >= 2 && wp < 2 + H_IN) {
    for (int c = l8; c < C_IN; c += 8) {
      float v = row[c * H_IN + (wp - 2)];
      sum += v * v;
    }
  }
  sum += __shfl_down(sum, 4, 8);
  sum += __shfl_down(sum, 2, 8);
  sum += __shfl_down(sum, 1, 8);
  if (l8 == 0) s[(n * HP + hp) * HP + wp] = sum;
}

// ---------------------------------------------------------------------------
// Kernel 2: W -> bf16 with K reordered to k' = rr*128 + ch (rr = dh*3+dw),
// plus wnorm[f] = 0.5*||W_f||^2 (fp32). grid 128, block 256.
// ---------------------------------------------------------------------------
__global__ void prep_w_kernel(const float* __restrict__ W,
                              unsigned short* __restrict__ Wbf,
                              float* __restrict__ wnorm) {
  int f = blockIdx.x;
  const float* Wf = W + f * K_TOT;
  float part = 0.f;
  for (int k = threadIdx.x; k < K_TOT; k += 256) {
    float v = Wf[k];                 // k = ch*9 + rr
    part += v * v;
    int ch = k / 9, rr = k % 9;
    Wbf[f * K_TOT + rr * 128 + ch] = f2bf(v);
  }
  __shared__ float red[256];
  red[threadIdx.x] = part;
  __syncthreads();
  for (int st = 128; st > 0; st >>= 1) {
    if (threadIdx.x < st) red[threadIdx.x] += red[threadIdx.x + st];
    __syncthreads();
  }
  if (threadIdx.x == 0) wnorm[f] = 0.5f * red[0];
}

// ---------------------------------------------------------------------------
// Kernel 3: xnorm[l] = 0.5 * sum over 3x3 window of s. l = n*900 + i*30 + j
// ---------------------------------------------------------------------------
__global__ void xnorm_kernel(const float* __restrict__ s,
                             float* __restrict__ xnorm) {
  int l = blockIdx.x * 256 + threadIdx.x;
  if (l >= L_TOT) return;
  int n = l / P_SP, p = l % P_SP, i = p / HO, j = p % HO;
  const float* sn = s + n * (HP * HP);
  float acc = 0.f;
#pragma unroll
  for (int dh = 0; dh < 3; dh++)
#pragma unroll
    for (int dw = 0; dw < 3; dw++)
      acc += sn[(i + dh) * HP + (j + dw)];
  xnorm[l] = 0.5f * acc;
}

// ---------------------------------------------------------------------------
// Kernel 4: implicit-im2col GEMM with bf16 MFMA.
// Tile: BM=128 (all f) x BL=64 cols, BK=128 (one window position per K-step).
// 256 threads = 4 waves (2x2), each wave computes 64(f) x 32(l).
// LDS rows are 256 B, k-contiguous, XOR-swizzled: byte ^= (row&7)<<4.
// Staged with global_load_lds(16B): linear LDS dest, inverse-swizzled source.
// ---------------------------------------------------------------------------
#define BL 64

__global__ __launch_bounds__(256, 2) void adder_gemm_kernel(
    const unsigned short* __restrict__ Wbf,
    const unsigned short* __restrict__ xcl,
    const float* __restrict__ wnorm,
    const float* __restrict__ xnorm,
    float* __restrict__ out) {
  __shared__ unsigned short A_lds[128 * 128];   // 32 KB: 128 f-rows x 256 B
  __shared__ unsigned short B_lds[BL * 128];    // 16 KB: 64 col-rows x 256 B

  int tid = threadIdx.x;
  int lane = tid & 63, wid = tid >> 6;
  int L0 = blockIdx.x * BL;

  const char* WbfB = (const char*)Wbf;
  const char* xclB = (const char*)xcl;
  char* AB = (char*)A_lds;
  char* BB = (char*)B_lds;

  // --- staging address precompute (per-thread, constant across K loop up to
  //     a per-step additive offset) ---
  int a_goff[8], a_loff[8];
#pragma unroll
  for (int a = 0; a < 8; a++) {
    int q = a * 4 + wid;                 // 1KB chunk id, 32 chunks total
    int rowf = q * 4 + (lane >> 4);      // f row (0..127)
    int b = (lane & 15) * 16;            // byte-in-row actually written
    int kb = b ^ ((rowf & 7) << 4);      // logical k-byte that lives there
    a_goff[a] = rowf * (K_TOT * 2) + kb; // + rr*256 per step
    a_loff[a] = q * 1024 + lane * 16;    // linear LDS byte offset
  }
  int b_goff[4], b_loff[4];
#pragma unroll
  for (int bb = 0; bb < 4; bb++) {
    int q = bb * 4 + wid;                // 16 chunks total
    int cc = q * 4 + (lane >> 4);        // tile column (0..63)
    int b = (lane & 15) * 16;
    int kb = b ^ ((cc & 7) << 4);
    int l = L0 + cc;
    int n = l / P_SP, p = l % P_SP, i = p / HO, j = p % HO;
    b_goff[bb] = (n * (HP * HP) + i * HP + j) * (C_IN * 2) + kb; // + (dh*32+dw)*256 per step
    b_loff[bb] = q * 1024 + lane * 16;
  }

  f32x4 acc[4][2];
#pragma unroll
  for (int mi = 0; mi < 4; mi++)
#pragma unroll
    for (int ni = 0; ni < 2; ni++)
      acc[mi][ni] = (f32x4){0.f, 0.f, 0.f, 0.f};

  int wr = wid >> 1, wc = wid & 1;

  for (int rr = 0; rr < 9; rr++) {
    int dh = rr / 3, dw = rr % 3;
    int woffA = rr * 256;                    // bytes: rr*128 bf16
    int woffB = (dh * HP + dw) * (C_IN * 2); // bytes
#pragma unroll
    for (int a = 0; a < 8; a++)
      __builtin_amdgcn_global_load_lds(
          (const __attribute__((address_space(1))) void*)(WbfB + a_goff[a] + woffA),
          (__attribute__((address_space(3))) void*)(AB + a_loff[a]), 16, 0, 0);
#pragma unroll
    for (int bb = 0; bb < 4; bb++)
      __builtin_amdgcn_global_load_lds(
          (const __attribute__((address_space(1))) void*)(xclB + b_goff[bb] + woffB),
          (__attribute__((address_space(3))) void*)(BB + b_loff[bb]), 16, 0, 0);
    __syncthreads();

#pragma unroll
    for (int kc = 0; kc < 4; kc++) {
      int kbl = kc * 64 + (lane >> 4) * 16;  // logical k-byte for this frag
      bf16x8 af[4], bfr[2];
#pragma unroll
      for (int mi = 0; mi < 4; mi++) {
        int rowf = wr * 64 + mi * 16 + (lane & 15);
        af[mi] = *(const bf16x8*)(AB + rowf * 256 + (kbl ^ ((rowf & 7) << 4)));
      }
#pragma unroll
      for (int ni = 0; ni < 2; ni++) {
        int cc = wc * 32 + ni * 16 + (lane & 15);
        bfr[ni] = *(const bf16x8*)(BB + cc * 256 + (kbl ^ ((cc & 7) << 4)));
      }
#pragma unroll
      for (int mi = 0; mi < 4; mi++)
#pragma unroll
        for (int ni = 0; ni < 2; ni++)
          acc[mi][ni] = __builtin_amdgcn_mfma_f32_16x16x32_bf16(
              af[mi], bfr[ni], acc[mi][ni], 0, 0, 0);
    }
    __syncthreads();
  }

  // Epilogue: subtract norms, scatter to (N, F, 30, 30).
  // C/D layout: col = lane&15, row = (lane>>4)*4 + r  [m89-verified]
#pragma unroll
  for (int ni = 0; ni < 2; ni++) {
    int cc = wc * 32 + ni * 16 + (lane & 15);
    int l = L0 + cc;
    float xn = xnorm[l];
    int n = l / P_SP, p = l % P_SP;
    float* outnp = out + n * (F_OUT * P_SP) + p;
#pragma unroll
    for (int mi = 0; mi < 4; mi++) {
      int f0 = wr * 64 + mi * 16 + (lane >> 4) * 4;
#pragma unroll
      for (int r = 0; r < 4; r++) {
        int f = f0 + r;
        outnp[f * P_SP] = acc[mi][ni][r] - wnorm[f] - xn;
      }
    }
  }
}

// ---------------------------------------------------------------------------
extern "C" void kernel_launch(void* const* d_in, const int* in_sizes, int n_in,
                              void* d_out, int out_size, void* d_ws, size_t ws_size,
                              hipStream_t stream) {
  const float* x = (const float*)d_in[0];
  const float* W = (const float*)d_in[1];
  float* out = (float*)d_out;

  // workspace layout (bytes)
  char* ws = (char*)d_ws;
  unsigned short* xcl = (unsigned short*)(ws);                   // 8,388,608 B
  unsigned short* Wbf = (unsigned short*)(ws + 8388608);         //   294,912 B
  float* wnorm = (float*)(ws + 8683520);                         //       512 B
  float* xnorm = (float*)(ws + 8684032);                         //   115,200 B
  float* s     = (float*)(ws + 8799232);                         //   131,072 B
  // total ~8.93 MB

  prep_x_kernel<<<dim3(N_IMG, HP), 256, 0, stream>>>(x, xcl, s);
  prep_w_kernel<<<F_OUT, 256, 0, stream>>>(W, Wbf, wnorm);
  xnorm_kernel<<<(L_TOT + 255) / 256, 256, 0, stream>>>(s, xnorm);
  adder_gemm_kernel<<<L_TOT / BL, 256, 0, stream>>>(Wbf, xcl, wnorm, xnorm, out);
}